// Round 2
// baseline (177.041 us; speedup 1.0000x reference)
//
#include <hip/hip_runtime.h>
#include <math.h>

#define T_LEN 1024
#define VV 512
#define BB 64
#define NB 16
#define ANG_STEP 0.006135923151542565f   // 2*pi/1024
#define FADE_S 487
#define FADE_E 537

__device__ constexpr int KB[NB] = {1,2,3,4,5,6,7,8,12,16,24,32,48,64,96,128};
// cos/sin(2*pi*k/1024) as literals so the rotation recurrence has no runtime sincos
__device__ constexpr float CWT[NB] = {
    0.9999811753f, 0.9999247018f, 0.9998305818f, 0.9996988187f,
    0.9995294175f, 0.9993223846f, 0.9990777278f, 0.9987954562f,
    0.9972904567f, 0.9951847267f, 0.9891765100f, 0.9807852804f,
    0.9569403357f, 0.9238795325f, 0.8314696123f, 0.7071067812f};
__device__ constexpr float SWT[NB] = {
    0.0061358846f, 0.0122715383f, 0.0184067299f, 0.0245412285f,
    0.0306748032f, 0.0368072229f, 0.0429382569f, 0.0490676743f,
    0.0735645636f, 0.0980171403f, 0.1467304745f, 0.1950903220f,
    0.2902846773f, 0.3826834324f, 0.5555702330f, 0.7071067812f};

// ---------------- Kernel 1: partial 16-bin DFT over a t-chunk ----------------
// grid (BB, TC), block 256. Thread owns v0=2*tid, v0+1. Rotation recurrence in regs.
// Partials: xp[((b*TC + tc)*32 + q)*VV + v], q in [0,16)=re_j, [16,32)=im_j
template<int TLEN>
__global__ __launch_bounds__(256) void k_dft_partial(const float* __restrict__ x,
                                                     float* __restrict__ xpart,
                                                     int tc_count) {
    const int b   = blockIdx.x;
    const int tc  = blockIdx.y;
    const int tid = threadIdx.x;
    const int t0  = tc * TLEN;

    float xr0[NB], xi0[NB], xr1[NB], xi1[NB], c[NB], s[NB];
#pragma unroll
    for (int j = 0; j < NB; ++j) {
        xr0[j] = xi0[j] = xr1[j] = xi1[j] = 0.0f;
        int n0 = (KB[j] * t0) & (T_LEN - 1);
        sincosf(ANG_STEP * (float)n0, &s[j], &c[j]);
    }

    const float2* xrd = (const float2*)(x + ((size_t)b * T_LEN + t0) * VV) + tid;

#define DFT_STEP(XV)                                            \
    do {                                                        \
        _Pragma("unroll")                                       \
        for (int j = 0; j < NB; ++j) {                          \
            xr0[j] = fmaf(XV.x, c[j], xr0[j]);                  \
            xi0[j] = fmaf(-XV.x, s[j], xi0[j]);                 \
            xr1[j] = fmaf(XV.y, c[j], xr1[j]);                  \
            xi1[j] = fmaf(-XV.y, s[j], xi1[j]);                 \
            float cn = fmaf(c[j], CWT[j], -(s[j] * SWT[j]));    \
            float sn = fmaf(s[j], CWT[j], c[j] * SWT[j]);       \
            c[j] = cn; s[j] = sn;                               \
        }                                                       \
    } while (0)

#pragma unroll 2
    for (int t = 0; t < TLEN; t += 4) {
        float2 a0 = xrd[(size_t)(t + 0) * (VV / 2)];
        float2 a1 = xrd[(size_t)(t + 1) * (VV / 2)];
        float2 a2 = xrd[(size_t)(t + 2) * (VV / 2)];
        float2 a3 = xrd[(size_t)(t + 3) * (VV / 2)];
        DFT_STEP(a0); DFT_STEP(a1); DFT_STEP(a2); DFT_STEP(a3);
    }
#undef DFT_STEP

    float2* o = (float2*)(xpart + (size_t)(b * tc_count + tc) * 32 * VV) + tid;
#pragma unroll
    for (int j = 0; j < NB; ++j) {
        o[(size_t)j        * (VV / 2)] = make_float2(xr0[j], xr1[j]);
        o[(size_t)(NB + j) * (VV / 2)] = make_float2(xi0[j], xi1[j]);
    }
}

// ---------------- Kernel 2: reduce partials, apply gains -> H ----------------
// H layout: H[b][q][v], q: [0,16)=He_re, [16,32)=-He_im, [32,48)=Hl_re, [48,64)=-Hl_im
// (2/T folded in; ims pre-negated so k_apply is pure fmaf)
__global__ __launch_bounds__(256) void k_combine(const float* __restrict__ xpart,
                                                 const float* __restrict__ ger,
                                                 const float* __restrict__ gei,
                                                 const float* __restrict__ glr,
                                                 const float* __restrict__ gli,
                                                 float* __restrict__ H, int tc_count) {
    const int b   = blockIdx.x;
    const int tid = threadIdx.x;
    const int v0  = tid * 2;

    float Xr0[NB], Xi0[NB], Xr1[NB], Xi1[NB];
#pragma unroll
    for (int j = 0; j < NB; ++j) { Xr0[j] = Xi0[j] = Xr1[j] = Xi1[j] = 0.0f; }

#pragma unroll 4
    for (int tc = 0; tc < tc_count; ++tc) {
        const float2* p = (const float2*)(xpart + (size_t)(b * tc_count + tc) * 32 * VV) + tid;
#pragma unroll
        for (int j = 0; j < NB; ++j) {
            float2 a  = p[(size_t)j        * (VV / 2)];
            float2 bb = p[(size_t)(NB + j) * (VV / 2)];
            Xr0[j] += a.x;  Xr1[j] += a.y;
            Xi0[j] += bb.x; Xi1[j] += bb.y;
        }
    }

    const float scale = 2.0f / (float)T_LEN;
    float2* o = (float2*)(H + (size_t)b * 64 * VV) + tid;
#pragma unroll
    for (int j = 0; j < NB; ++j) {
        float er0 = ger[v0 * NB + j],       ei0 = gei[v0 * NB + j];
        float lr0 = glr[v0 * NB + j],       li0 = gli[v0 * NB + j];
        float er1 = ger[(v0 + 1) * NB + j], ei1 = gei[(v0 + 1) * NB + j];
        float lr1 = glr[(v0 + 1) * NB + j], li1 = gli[(v0 + 1) * NB + j];

        float here0 = (Xr0[j] * er0 - Xi0[j] * ei0) * scale;
        float heim0 = (Xr0[j] * ei0 + Xi0[j] * er0) * scale;
        float hlre0 = (Xr0[j] * lr0 - Xi0[j] * li0) * scale;
        float hlim0 = (Xr0[j] * li0 + Xi0[j] * lr0) * scale;
        float here1 = (Xr1[j] * er1 - Xi1[j] * ei1) * scale;
        float heim1 = (Xr1[j] * ei1 + Xi1[j] * er1) * scale;
        float hlre1 = (Xr1[j] * lr1 - Xi1[j] * li1) * scale;
        float hlim1 = (Xr1[j] * li1 + Xi1[j] * lr1) * scale;

        o[(size_t)j        * (VV / 2)] = make_float2(here0, here1);
        o[(size_t)(16 + j) * (VV / 2)] = make_float2(-heim0, -heim1);
        o[(size_t)(32 + j) * (VV / 2)] = make_float2(hlre0, hlre1);
        o[(size_t)(48 + j) * (VV / 2)] = make_float2(-hlim0, -hlim1);
    }
}

// ---------------- Kernel 3: synthesize + crossfade + add x ----------------
// grid (BB, 16) t-tiles of 64, block 256, thread owns v0=2*tid, v0+1.
// Pure-early tiles use He only, pure-late use Hl only (half the fma);
// only the 2 tiles straddling the fade run the dual path.
#define ATL 64
__global__ __launch_bounds__(256) void k_apply(const float* __restrict__ x,
                                               const float* __restrict__ H,
                                               float* __restrict__ out) {
    const int b   = blockIdx.x;
    const int tb  = blockIdx.y;
    const int tid = threadIdx.x;
    const int t0  = tb * ATL;

    __shared__ float2 tab[T_LEN];
    for (int i = tid; i < T_LEN; i += 256) {
        float ss, cc;
        sincosf(ANG_STEP * (float)i, &ss, &cc);
        tab[i] = make_float2(cc, ss);
    }
    __syncthreads();

    const float2* hp  = (const float2*)(H + (size_t)b * 64 * VV) + tid;
    const float2* xrd = (const float2*)(x + ((size_t)b * T_LEN + t0) * VV) + tid;
    float2*       ow  = (float2*)(out + ((size_t)b * T_LEN + t0) * VV) + tid;

    const int mode = (t0 + ATL <= FADE_S) ? 0 : ((t0 >= FADE_E) ? 1 : 2);

    if (mode < 2) {
        // single-H path: He for early, Hl for late
        const int qo = mode ? 32 : 0;
        float hr0[NB], hi0[NB], hr1[NB], hi1[NB];
#pragma unroll
        for (int j = 0; j < NB; ++j) {
            float2 a  = hp[(size_t)(qo + j)      * (VV / 2)]; hr0[j] = a.x;  hr1[j] = a.y;
            float2 bq = hp[(size_t)(qo + 16 + j) * (VV / 2)]; hi0[j] = bq.x; hi1[j] = bq.y;
        }
#pragma unroll 2
        for (int t = 0; t < ATL; ++t) {
            const int tg = t0 + t;
            float2 xv = xrd[(size_t)t * (VV / 2)];
            float s0 = 0.f, s1 = 0.f;
#pragma unroll
            for (int j = 0; j < NB; ++j) {
                float2 cs = tab[(KB[j] * tg) & (T_LEN - 1)];
                s0 = fmaf(hr0[j], cs.x, s0); s0 = fmaf(hi0[j], cs.y, s0);
                s1 = fmaf(hr1[j], cs.x, s1); s1 = fmaf(hi1[j], cs.y, s1);
            }
            ow[(size_t)t * (VV / 2)] = make_float2(xv.x + s0, xv.y + s1);
        }
    } else {
        // fade path: needs both He and Hl
        float er0[NB], ei0[NB], er1[NB], ei1[NB];
        float lr0[NB], li0[NB], lr1[NB], li1[NB];
#pragma unroll
        for (int j = 0; j < NB; ++j) {
            float2 a  = hp[(size_t)j        * (VV / 2)]; er0[j] = a.x;  er1[j] = a.y;
            float2 bq = hp[(size_t)(16 + j) * (VV / 2)]; ei0[j] = bq.x; ei1[j] = bq.y;
            float2 cq = hp[(size_t)(32 + j) * (VV / 2)]; lr0[j] = cq.x; lr1[j] = cq.y;
            float2 dq = hp[(size_t)(48 + j) * (VV / 2)]; li0[j] = dq.x; li1[j] = dq.y;
        }
        for (int t = 0; t < ATL; ++t) {
            const int tg = t0 + t;
            float2 xv = xrd[(size_t)t * (VV / 2)];
            float se0 = 0.f, se1 = 0.f, sl0 = 0.f, sl1 = 0.f;
#pragma unroll
            for (int j = 0; j < NB; ++j) {
                float2 cs = tab[(KB[j] * tg) & (T_LEN - 1)];
                se0 = fmaf(er0[j], cs.x, se0); se0 = fmaf(ei0[j], cs.y, se0);
                se1 = fmaf(er1[j], cs.x, se1); se1 = fmaf(ei1[j], cs.y, se1);
                sl0 = fmaf(lr0[j], cs.x, sl0); sl0 = fmaf(li0[j], cs.y, sl0);
                sl1 = fmaf(lr1[j], cs.x, sl1); sl1 = fmaf(li1[j], cs.y, sl1);
            }
            float w = (tg < FADE_S) ? 1.0f
                    : ((tg < FADE_E) ? (1.0f - (float)(tg - FADE_S) * (1.0f / 50.0f)) : 0.0f);
            float2 ov;
            ov.x = xv.x + fmaf(w, se0 - sl0, sl0);
            ov.y = xv.y + fmaf(w, se1 - sl1, sl1);
            ow[(size_t)t * (VV / 2)] = ov;
        }
    }
}

extern "C" void kernel_launch(void* const* d_in, const int* in_sizes, int n_in,
                              void* d_out, int out_size, void* d_ws, size_t ws_size,
                              hipStream_t stream) {
    (void)in_sizes; (void)n_in; (void)out_size;
    const float* x   = (const float*)d_in[0];
    const float* ger = (const float*)d_in[1];
    const float* gei = (const float*)d_in[2];
    const float* glr = (const float*)d_in[3];
    const float* gli = (const float*)d_in[4];
    float* out = (float*)d_out;

    // workspace: partials (BB*TC*32*VV floats) + H (BB*64*VV floats)
    const size_t hflts = (size_t)BB * 64 * VV;
    int TC;
    if (((size_t)BB * 16 * 32 * VV + hflts) * sizeof(float) <= ws_size)      TC = 16;
    else if (((size_t)BB * 8 * 32 * VV + hflts) * sizeof(float) <= ws_size)  TC = 8;
    else                                                                     TC = 4;

    float* xpart = (float*)d_ws;
    float* H     = xpart + (size_t)BB * TC * 32 * VV;

    if (TC == 16)      k_dft_partial<64> <<<dim3(BB, 16), 256, 0, stream>>>(x, xpart, 16);
    else if (TC == 8)  k_dft_partial<128><<<dim3(BB, 8),  256, 0, stream>>>(x, xpart, 8);
    else               k_dft_partial<256><<<dim3(BB, 4),  256, 0, stream>>>(x, xpart, 4);

    k_combine<<<dim3(BB), 256, 0, stream>>>(xpart, ger, gei, glr, gli, H, TC);
    k_apply<<<dim3(BB, T_LEN / ATL), 256, 0, stream>>>(x, H, out);
}